// Round 6
// baseline (1171.534 us; speedup 1.0000x reference)
//
#include <hip/hip_runtime.h>
#include <cstdint>

// ---------------------------------------------------------------------------
// WindowAttention: pad 96->100, roll(+2,+2), 4x4 windows, MHA(8 heads,d=64),
// un-window, roll back, crop. WINDOW-MAJOR token order:
//   m = (g*625 + (hh/4)*25 + (ww/4))*16 + (hh%4)*4 + (ww%4)
// Single pass (G=16, Mp=160000):
//   gather -> qkv GEMM (256^2, 2-phase dbuf) -> window attn
//   -> out GEMM (transposed, fused LDS-transpose scatter epilogue)
// ---------------------------------------------------------------------------

typedef __attribute__((ext_vector_type(8))) __bf16 bf16x8;
typedef __attribute__((ext_vector_type(8))) uint16_t u16x8;
typedef __attribute__((ext_vector_type(4))) float f32x4;

__device__ __forceinline__ uint16_t f2bf(float f) {
  union { float f; uint32_t u; } c; c.f = f;
  uint32_t r = c.u + 0x7FFFu + ((c.u >> 16) & 1u);  // RNE
  return (uint16_t)(r >> 16);
}
__device__ __forceinline__ float bf2f(uint16_t u) {
  union { uint32_t u; float f; } c; c.u = ((uint32_t)u) << 16;
  return c.f;
}

__device__ __forceinline__ void g2lds16(const void* g, void* lds) {
  __builtin_amdgcn_global_load_lds(
      (const __attribute__((address_space(1))) uint32_t*)(uintptr_t)g,
      (__attribute__((address_space(3))) uint32_t*)(uintptr_t)lds,
      16, 0, 0);
}

#define CFENCE asm volatile("" ::: "memory")
#define BAR do { CFENCE; __builtin_amdgcn_s_barrier(); CFENCE; } while (0)

// ---------------------------------------------------------------------------
__global__ void cvt_weights(const float* __restrict__ w1, const float* __restrict__ w2,
                            uint16_t* __restrict__ o1, uint16_t* __restrict__ o2) {
  int i = blockIdx.x * 256 + threadIdx.x;
  if (i < 786432) o1[i] = f2bf(w1[i]);
  if (i < 262144) o2[i] = f2bf(w2[i]);
}

// ---------------------------------------------------------------------------
// Gather: x (NCHW fp32) -> window-major token-major bf16 X[m,512].
// ---------------------------------------------------------------------------
__global__ __launch_bounds__(256) void gather_kernel(
    const float* __restrict__ x, uint16_t* __restrict__ xbf, int n0) {
  __shared__ float tile[64][65];
  const int z = blockIdx.z;
  const int g = z / 100, hh = z % 100;
  const int c0 = blockIdx.y * 64, ww0 = blockIdx.x * 64;
  const int n = n0 + g;
  const int hp = (hh >= 2) ? hh - 2 : hh + 98;
  const bool hok = hp < 96;
  const int t = threadIdx.x;
  const int lane = t & 63, grp = t >> 6;

  const int ww = ww0 + lane;
  const int wp = (ww >= 2) ? ww - 2 : ww + 98;
  const bool wok = hok && (ww < 100) && (wp < 96);
  const float* xb = x + ((size_t)n * 512) * 9216 + (size_t)hp * 96 + wp;
#pragma unroll
  for (int i = 0; i < 16; ++i) {
    int c = grp + i * 4;
    tile[c][lane] = wok ? xb[(size_t)(c0 + c) * 9216] : 0.f;
  }
  __syncthreads();
#pragma unroll
  for (int i = 0; i < 16; ++i) {
    int wl = grp + i * 4;
    int www = ww0 + wl;
    if (www < 100) {
      int m = (g * 625 + (hh >> 2) * 25 + (www >> 2)) * 16 + (hh & 3) * 4 + (www & 3);
      xbf[(size_t)m * 512 + c0 + lane] = f2bf(tile[lane][wl]);
    }
  }
}

// ---------------------------------------------------------------------------
// 2-phase double-buffered 256x256 GEMM, BK=64, K=512, 512 thr (8 waves 2Mx4N).
// Guide T3-minimum recipe: per K-tile { STAGE(next -> buf^1); ds_read all
// frags from buf[cur]; setprio(1); 64 MFMA; setprio(0); vmcnt(0); BAR }.
// One barrier per K-tile -> wave-level ds_read/MFMA overlap on each SIMD.
// LDS 128KB (2 bufs x (A 32KB + B 32KB)), XOR-swizzled (byte ^= (row&7)<<4)
// via pre-swizzled global source + swizzled ds_read.
// D[row,col] = sum_k A[row,k]*B[col,k]; both row-major, stride 512.
// EPI 0 (qkv): scalar bf16 stores +bias[col]  (R2-proven pair, unswapped MM).
// EPI 1 (out): LDS-transpose epilogue scattering fp32 (c,hh)-rows to NCHW.
// ---------------------------------------------------------------------------
template <int EPI, int NB, int MODE>
__global__ __launch_bounds__(512, 2) void gemm2(
    const uint16_t* __restrict__ A, const uint16_t* __restrict__ B,
    const float* __restrict__ bias, uint16_t* __restrict__ Cbf,
    float* __restrict__ Cout, int Mg, int n0) {
  __shared__ alignas(16) uint16_t lds[65536];  // 128 KB: buf[2] x (A|B)
  const int t = threadIdx.x;
  const int w = t >> 6, lane = t & 63;
  const int wr = w >> 2, wc = w & 3;
  const int lr = lane & 15, lg = lane >> 4;

  // bijective XCD swizzle
  const int nwg = gridDim.x, bid = blockIdx.x;
  const int q = nwg >> 3, r = nwg & 7;
  const int xc = bid & 7, li = bid >> 3;
  const int wg = (xc < r ? xc * (q + 1) : r * (q + 1) + (xc - r) * q) + li;
  int bm, bn;
  if (MODE == 0) { bm = wg / NB; bn = wg % NB; }
  else           { bm = wg % NB; bn = wg / NB; }

  // stage full K-tile (A 32KB + B 32KB) into buffer b; 8 g2lds/thread
  auto STAGE = [&](int kt, int b) {
#pragma unroll
    for (int i = 0; i < 4; ++i) {
      int e = i * 512 + t;
      int row = e >> 3, slot = e & 7;
      const uint16_t* ga = A + (size_t)(bm * 256 + row) * 512 + kt * 64 +
                           ((slot ^ (row & 7)) << 3);
      const uint16_t* gb = B + (size_t)(bn * 256 + row) * 512 + kt * 64 +
                           ((slot ^ (row & 7)) << 3);
      g2lds16(ga, &lds[b * 32768 + ((i * 512 + w * 64) << 3)]);
      g2lds16(gb, &lds[b * 32768 + 16384 + ((i * 512 + w * 64) << 3)]);
    }
  };
  auto LDA = [&](int b, int mi, int k2) -> bf16x8 {
    int row = wr * 128 + mi * 16 + lr;
    int byte = b * 65536 + row * 128 + ((k2 * 64 + lg * 16) ^ ((row & 7) << 4));
    return *(const bf16x8*)((const char*)lds + byte);
  };
  auto LDB = [&](int b, int ni, int k2) -> bf16x8 {
    int row = wc * 64 + ni * 16 + lr;
    int byte = b * 65536 + 32768 + row * 128 +
               ((k2 * 64 + lg * 16) ^ ((row & 7) << 4));
    return *(const bf16x8*)((const char*)lds + byte);
  };

  f32x4 acc[8][4];
#pragma unroll
  for (int mi = 0; mi < 8; ++mi)
#pragma unroll
    for (int ni = 0; ni < 4; ++ni) acc[mi][ni] = (f32x4){0.f, 0.f, 0.f, 0.f};

  STAGE(0, 0);
  asm volatile("s_waitcnt vmcnt(0)" ::: "memory");
  BAR;

  int cur = 0;
  for (int k = 0; k < 8; ++k) {
    if (k + 1 < 8) STAGE(k + 1, cur ^ 1);   // prefetch next tile (overlaps below)
    bf16x8 af[8][2], bf[4][2];
#pragma unroll
    for (int mi = 0; mi < 8; ++mi)
#pragma unroll
      for (int k2 = 0; k2 < 2; ++k2) af[mi][k2] = LDA(cur, mi, k2);
#pragma unroll
    for (int ni = 0; ni < 4; ++ni)
#pragma unroll
      for (int k2 = 0; k2 < 2; ++k2) bf[ni][k2] = LDB(cur, ni, k2);
    __builtin_amdgcn_s_setprio(1);
#pragma unroll
    for (int mi = 0; mi < 8; ++mi)
#pragma unroll
      for (int ni = 0; ni < 4; ++ni)
#pragma unroll
        for (int k2 = 0; k2 < 2; ++k2)
          acc[mi][ni] = __builtin_amdgcn_mfma_f32_16x16x32_bf16(
              af[mi][k2], bf[ni][k2], acc[mi][ni], 0, 0, 0);
    __builtin_amdgcn_s_setprio(0);
    asm volatile("s_waitcnt vmcnt(0)" ::: "memory");  // next tile landed
    BAR;                                              // all waves done reading cur
    cur ^= 1;
  }

  if (EPI == 0) {
    // row = bm*256 + wr*128 + mi*16 + lg*4 + rr ; col = bn*256 + wc*64 + ni*16 + lr
#pragma unroll
    for (int ni = 0; ni < 4; ++ni) {
      int col = bn * 256 + wc * 64 + ni * 16 + lr;
      float bb = bias[col];
#pragma unroll
      for (int mi = 0; mi < 8; ++mi) {
        int row = bm * 256 + wr * 128 + mi * 16 + lg * 4;
#pragma unroll
        for (int rr = 0; rr < 4; ++rr)
          Cbf[(size_t)(row + rr) * 1536 + col] = f2bf(acc[mi][ni][rr] + bb);
      }
    }
  } else {
    __syncthreads();
    // acc: c = bm*256 + wr*128 + mi*16 + lg*4 + rr ; tok = bn*256 + wc*64 + ni*16 + lr
    float* ldsF = (float*)lds;  // [256][68] fp32 = 68KB <= 128KB
    const int Gwin = Mg >> 4;
#pragma unroll
    for (int p = 0; p < 4; ++p) {
      if (wc == p) {
#pragma unroll
        for (int mi = 0; mi < 8; ++mi) {
          const float* b4 = &bias[bm * 256 + wr * 128 + mi * 16 + lg * 4];
#pragma unroll
          for (int ni = 0; ni < 4; ++ni)
#pragma unroll
            for (int rr = 0; rr < 4; ++rr)
              ldsF[(wr * 128 + mi * 16 + lg * 4 + rr) * 68 + ni * 16 + lr] =
                  acc[mi][ni][rr] + b4[rr];
        }
      }
      __syncthreads();
#pragma unroll
      for (int i = 0; i < 8; ++i) {
        int e = i * 512 + t;                   // 4096 16B-runs
        int w4 = e & 3, rrow = (e >> 2) & 3, c = e >> 4;
        int cw = bn * 16 + p * 4 + w4;         // window id
        if (cw < Gwin) {
          int g = cw / 625, wid = cw % 625;
          int ib = wid / 25, jb = wid % 25;
          int hh = ib * 4 + rrow;
          if (hh >= 2 && hh < 98) {
            float4 v = *(const float4*)&ldsF[c * 68 + w4 * 16 + rrow * 4];
            size_t base = ((size_t)(n0 + g) * 512 + bm * 256 + c) * 9216 +
                          (size_t)(hh - 2) * 96;
            if (jb >= 1 && jb < 24) {
              float* pp = &Cout[base + jb * 4 - 2];
              float2 lo; lo.x = v.x; lo.y = v.y;
              float2 hi; hi.x = v.z; hi.y = v.w;
              *(float2*)pp = lo;
              *(float2*)(pp + 2) = hi;
            } else if (jb == 0) {
              Cout[base + 0] = v.z; Cout[base + 1] = v.w;   // ww=2,3
            } else {
              Cout[base + 94] = v.x; Cout[base + 95] = v.y; // ww=96,97
            }
          }
        }
      }
      __syncthreads();
    }
  }
}

// ---------------------------------------------------------------------------
// Attention: 1 block/window, 128 thr = (head h, query qi). K/V staged in LDS
// (32KB -> high occupancy), Q read direct. fp32 VALU softmax.
// ---------------------------------------------------------------------------
__global__ __launch_bounds__(128) void attn_kernel(
    const uint16_t* __restrict__ qkv, const float* __restrict__ x,
    uint16_t* __restrict__ obuf, int n0) {
  __shared__ alignas(16) uint16_t skv[16][1024];  // [row][K(512) V(512)]
  __shared__ float smask[16];
  const int b = blockIdx.x;
  const int g = b / 625, wid = b % 625;
  const int ib = wid / 25, jb = wid % 25;
  const int t = threadIdx.x;
  const int wv = t >> 6;
  const int mbase = b * 16;   // window-major base row
  const int h = t >> 4, qi = t & 15;

  // stage K+V (qkv cols 512..1536 contiguous) via global_load_lds
#pragma unroll
  for (int it = 0; it < 16; ++it) {
    int e = it * 128 + t;                 // 16B chunk id in [0,2048)
    int l = e >> 7, c = e & 127;
    const uint16_t* src = qkv + (size_t)(mbase + l) * 1536 + 512 + c * 8;
    g2lds16(src, (uint16_t*)skv + (it * 128 + wv * 64) * 8);
  }
  // Q direct loads (overlap staging)
  float qv[64];
#pragma unroll
  for (int d8 = 0; d8 < 8; ++d8) {
    u16x8 v = *(const u16x8*)&qkv[(size_t)(mbase + qi) * 1536 + h * 64 + d8 * 8];
#pragma unroll
    for (int j = 0; j < 8; ++j) qv[d8 * 8 + j] = bf2f(v[j]);
  }
  if (t < 16) {
    int hh = ib * 4 + (t >> 2), ww = jb * 4 + (t & 3);
    int a = (hh >= 4) ? hh - 4 : hh + 96;
    int c = (ww >= 4) ? ww - 4 : ww + 96;
    smask[t] = (a < 96 && c < 96)
                   ? x[((size_t)(n0 + g) * 512) * 9216 + (size_t)a * 96 + c]
                   : 0.f;
  }
  __syncthreads();

  float s[16];
  float mx = -1e30f;
#pragma unroll
  for (int ki = 0; ki < 16; ++ki) {
    float a = 0.f;
#pragma unroll
    for (int d8 = 0; d8 < 8; ++d8) {
      u16x8 kv = *(const u16x8*)&skv[ki][h * 64 + d8 * 8];
#pragma unroll
      for (int j = 0; j < 8; ++j) a += qv[d8 * 8 + j] * bf2f(kv[j]);
    }
    s[ki] = a * 0.125f + smask[ki];
    mx = fmaxf(mx, s[ki]);
  }
  float sum = 0.f;
#pragma unroll
  for (int ki = 0; ki < 16; ++ki) { s[ki] = __expf(s[ki] - mx); sum += s[ki]; }
  const float inv = 1.f / sum;
  float o[64];
#pragma unroll
  for (int d = 0; d < 64; ++d) o[d] = 0.f;
#pragma unroll
  for (int ki = 0; ki < 16; ++ki) {
    float wgt = s[ki] * inv;
#pragma unroll
    for (int d8 = 0; d8 < 8; ++d8) {
      u16x8 vv = *(const u16x8*)&skv[ki][512 + h * 64 + d8 * 8];
#pragma unroll
      for (int j = 0; j < 8; ++j) o[d8 * 8 + j] += wgt * bf2f(vv[j]);
    }
  }
  const int m = mbase + qi;
#pragma unroll
  for (int d8 = 0; d8 < 8; ++d8) {
    alignas(16) uint16_t tmp[8];
#pragma unroll
    for (int j = 0; j < 8; ++j) tmp[j] = f2bf(o[d8 * 8 + j]);
    *(uint4*)&obuf[(size_t)m * 512 + h * 64 + d8 * 8] = *(uint4*)tmp;
  }
}

// ---------------------------------------------------------------------------
extern "C" void kernel_launch(void* const* d_in, const int* in_sizes, int n_in,
                              void* d_out, int out_size, void* d_ws, size_t ws_size,
                              hipStream_t stream) {
  const float* x  = (const float*)d_in[0];
  const float* wq = (const float*)d_in[1];
  const float* bq = (const float*)d_in[2];
  const float* wo = (const float*)d_in[3];
  const float* bo = (const float*)d_in[4];
  float* out = (float*)d_out;
  uint8_t* ws = (uint8_t*)d_ws;

  uint16_t* wq_bf = (uint16_t*)ws;               // 1.5 MB
  uint16_t* wo_bf = (uint16_t*)(ws + 1572864);   // 0.5 MB
  uint8_t* bufbase = ws + 2097152;

  int G = 16;   // single pass: full grids, 5 launches total
  while (G > 1) {
    int Mg = G * 10000;
    int Mp = ((Mg + 255) / 256) * 256;
    size_t need = (size_t)2097152 + (size_t)Mp * 4096;
    if (need <= ws_size) break;
    G >>= 1;
  }
  const int Mg = G * 10000;
  const int Mp = ((Mg + 255) / 256) * 256;
  uint16_t* xo   = (uint16_t*)bufbase;                        // Mp*512 (X, then O)
  uint16_t* qkvb = (uint16_t*)(bufbase + (size_t)Mp * 1024);  // Mp*1536

  cvt_weights<<<dim3(3072), dim3(256), 0, stream>>>(wq, wo, wq_bf, wo_bf);

  for (int n0 = 0; n0 < 16; n0 += G) {
    gather_kernel<<<dim3(2, 8, G * 100), dim3(256), 0, stream>>>(x, xo, n0);
    // qkv[m,1536] = X @ Wqkv^T + b
    gemm2<0, 6, 0><<<dim3((Mp / 256) * 6), dim3(512), 0, stream>>>(
        xo, wq_bf, bq, qkvb, nullptr, Mg, n0);
    attn_kernel<<<dim3(G * 625), dim3(128), 0, stream>>>(qkvb, x, xo, n0);
    // out[c,tok] = Wout @ O^T + b, scattered to (N,C,96,96)
    gemm2<1, 2, 1><<<dim3((Mp / 256) * 2), dim3(512), 0, stream>>>(
        wo_bf, xo, bo, nullptr, out, Mg, n0);
  }
  (void)in_sizes; (void)n_in; (void)out_size;
}